// Round 8
// baseline (1733.200 us; speedup 1.0000x reference)
//
#include <hip/hip_runtime.h>

using bf16x8 = __attribute__((ext_vector_type(8))) __bf16;
using f32x4  = __attribute__((ext_vector_type(4))) float;

#define BM 256
#define BN 256

// ---------------------------------------------------------------- fused GEMM
// out[T,O] = x[T,K](fp32->bf16) * dequant(w_q[O,K])^T + bias[O].
// R5's proven 8-phase schedule (253-257us, MfmaUtil 47%, 0 bank conflicts)
// with staging FUSED: no prep kernels, no workspace.  Reg-staging (T14
// issue/commit split) replaces global_load_lds:
//   ISSUE  at phase p:   4x vec4 global loads/thread (fp32 x or int32 w_q)
//   COMMIT at phase p+2: cvt->bf16 (dequant for W), 2x ds_write_b128
// Staging RAW is register-carried -> compiler inserts exact counted vmcnt
// before each commit's cvt (never drains to 0: T4 preserved).  ds_write
// visibility: commit's write is drained by that phase's mid LGKM0 (before
// the phase-end barrier); first read >=1 barrier later.
//
// LDS (128 KiB): A tiles [2][256][64]bf16 at 0, B tiles at 65536.  Same
// swizzle as R2-R7: phys chunk p holds logical (row=p>>7, slot=(p>>7&7)^
// (p>>4&7)) -- writes are LINEAR phys (conflict-free), source address is
// deswizzled, reads use sb0/sb1 XOR offsets (verified 0 conflicts).
//
// Per iteration = 2 K-tiles: buf0 = Kt(2i) [ke0] phases 0-3, buf1 =
// Kt(2i+1) [ke0+64] phases 4-7.  Reads + MFMA (R5 verbatim):
//   P0: a[m0-3]+b[n0-1] (12 rd) QUAD(0,0)   P4: same on buf1
//   P1: b[n2-3]          (4 rd) QUAD(0,2)   P5: ...
//   P2: a[m4-7]          (8 rd) QUAD(4,2)   P6: ...
//   P3: (none)                  QUAD(4,0)   P7: ...
// Stage slots (ISSUE@p -> COMMIT@p+2; regs vA0/vA1/vB0/vB1 each reused
// every 4 phases, commit-read 2 phases before re-issue):
//   P0: IS vA0(ht0,ke0+64)  CM vB0->buf1.B0   (buf1.B last read prev-P5)
//   P1: IS vA1(ht1,ke0+64)  CM vB1->buf1.B1
//   P2: IS vB0(ht0,ke0+128) CM vA0->buf1.A0   (buf1.A last read prev-P6)
//   P3: IS vB1(ht1,ke0+128) CM vA1->buf1.A1   (read P4: 1 barrier after)
//   P4: IS vA0(ht0,ke0+128) CM vB0->buf0.B0   (buf0.B read P0/P1: done)
//   P5: IS vA1(ht1,ke0+128) CM vB1->buf0.B1
//   P6: IS vB0(ht0,ke0+192) CM vA0->buf0.A0   (buf0.A read P0/P2: done)
//   P7: IS vB1(ht1,ke0+192) CM vA1->buf0.A1   (read next-P0: 1 barrier)
// Tail issues wrap ke mod K (in-bounds, committed-but-unread).  Prologue:
// issue+commit buf0 (4 half-tiles) + issue buf1.B -> matches steady state.
#define REGA 0
#define REGB 65536

#define BARRIER()  __builtin_amdgcn_s_barrier()
#define LGKM0()    asm volatile("s_waitcnt lgkmcnt(0)" ::: "memory")
#define PRIO1()    __builtin_amdgcn_s_setprio(1)
#define PRIO0()    __builtin_amdgcn_s_setprio(0)

__global__ __launch_bounds__(512, 2) void gemm_fused(
    const float* __restrict__ x, const int* __restrict__ wq,
    const float* __restrict__ sc, const float* __restrict__ bias,
    float* __restrict__ C, int M, int N, int K) {
    __shared__ char lds[131072] __attribute__((aligned(16)));
    char* const ldsb = lds;

    const int tid  = threadIdx.x;
    const int wave = tid >> 6;
    const int lane = tid & 63;
    const int r = lane & 15;          // MFMA operand: m/n index = lane&15
    const int q = lane >> 4;          // k = q*8 + j
    const int wm = (wave >> 2) * 128; // 2 M-waves
    const int wn = (wave & 3) * 64;   // 4 N-waves

    // Bijective XCD swizzle (m204).
    const int nwg = gridDim.x;
    const int q8 = nwg >> 3, r8 = nwg & 7;
    const int xcd = blockIdx.x & 7, seq = blockIdx.x >> 3;
    const int swz = (xcd < r8 ? xcd * (q8 + 1)
                              : r8 * (q8 + 1) + (xcd - r8) * q8) + seq;
    const int nTiles = N / BN;
    const int row0 = (swz / nTiles) * BM;
    const int col0 = (swz % nTiles) * BN;

    const int nsb = K >> 5;   // scale blocks per W row

    // Staging geometry: thread owns phys chunks p=(it*512+tid)*16 of a
    // 16 KiB half-tile (128 rows x 128B bf16).  Deswizzled source element:
    // row gr, element gcE (0..63).
    const float* srcAx[2];
    const int*   srcWq[2];
    int scRow[2], keOff[2];
#pragma unroll
    for (int it = 0; it < 2; ++it) {
        const int p   = (it * 512 + tid) * 16;
        const int lin = p ^ (((p >> 7) & 7) << 4);
        const int gr  = lin >> 7;            // row within half-tile
        const int gcE = (lin & 127) >> 1;    // element offset (mult of 8)
        srcAx[it] = x  + (size_t)(row0 + gr) * K + gcE;
        srcWq[it] = wq + (size_t)(col0 + gr) * K + gcE;
        scRow[it] = (col0 + gr) * nsb;
        keOff[it] = gcE;
    }

#define ISSUE_A(V, ht, ke) do { _Pragma("unroll")                            \
        for (int it = 0; it < 2; ++it) {                                     \
            const float* s_ = srcAx[it] + (size_t)(ht) * 128 * K + (ke);     \
            V[it][0] = *(const float4*)s_;                                   \
            V[it][1] = *(const float4*)(s_ + 4);                             \
        } } while (0)

#define ISSUE_B(V, S, ht, ke) do { _Pragma("unroll")                         \
        for (int it = 0; it < 2; ++it) {                                     \
            const int* s_ = srcWq[it] + (size_t)(ht) * 128 * K + (ke);       \
            V[it][0] = *(const int4*)s_;                                     \
            V[it][1] = *(const int4*)(s_ + 4);                               \
            S[it] = sc[scRow[it] + (ht) * 128 * nsb                          \
                       + (((ke) + keOff[it]) >> 5)];                         \
        } } while (0)

#define COMMIT_A(V, buf, ht) do { _Pragma("unroll")                          \
        for (int it = 0; it < 2; ++it) {                                     \
            bf16x8 v;                                                        \
            v[0] = (__bf16)V[it][0].x; v[1] = (__bf16)V[it][0].y;            \
            v[2] = (__bf16)V[it][0].z; v[3] = (__bf16)V[it][0].w;            \
            v[4] = (__bf16)V[it][1].x; v[5] = (__bf16)V[it][1].y;            \
            v[6] = (__bf16)V[it][1].z; v[7] = (__bf16)V[it][1].w;            \
            *(bf16x8*)(ldsb + REGA + (buf) * 32768 + (ht) * 16384            \
                       + (it * 512 + tid) * 16) = v;                         \
        } } while (0)

#define COMMIT_B(V, S, buf, ht) do { _Pragma("unroll")                       \
        for (int it = 0; it < 2; ++it) {                                     \
            const float s_ = S[it];                                          \
            bf16x8 v;                                                        \
            v[0] = (__bf16)((float)(V[it][0].x - 128) * s_);                 \
            v[1] = (__bf16)((float)(V[it][0].y - 128) * s_);                 \
            v[2] = (__bf16)((float)(V[it][0].z - 128) * s_);                 \
            v[3] = (__bf16)((float)(V[it][0].w - 128) * s_);                 \
            v[4] = (__bf16)((float)(V[it][1].x - 128) * s_);                 \
            v[5] = (__bf16)((float)(V[it][1].y - 128) * s_);                 \
            v[6] = (__bf16)((float)(V[it][1].z - 128) * s_);                 \
            v[7] = (__bf16)((float)(V[it][1].w - 128) * s_);                 \
            *(bf16x8*)(ldsb + REGB + (buf) * 32768 + (ht) * 16384            \
                       + (it * 512 + tid) * 16) = v;                         \
        } } while (0)

    // Fragment-read swizzled offsets (unchanged from R2-R7).
    const int sb0 = (q ^ (r & 7)) * 16;
    const int sb1 = ((4 + q) ^ (r & 7)) * 16;
    const int aBase = REGA + (wm + r) * 128;
    const int bBase = REGB + (wn + r) * 128;

    bf16x8 afr[4][2];
    bf16x8 bfr[4][2];
    f32x4  acc[8][4];
    const f32x4 zero = {0.f, 0.f, 0.f, 0.f};
#pragma unroll
    for (int i = 0; i < 8; ++i)
#pragma unroll
        for (int j = 0; j < 4; ++j) acc[i][j] = zero;

#define LDA4(buf, mb) do { _Pragma("unroll")                                 \
        for (int mm = 0; mm < 4; ++mm) {                                     \
            const char* pa = ldsb + (buf) * 32768 + aBase + ((mb) + mm) * 2048; \
            afr[mm][0] = *(const bf16x8*)(pa + sb0);                         \
            afr[mm][1] = *(const bf16x8*)(pa + sb1);                         \
        } } while (0)

#define LDB2(buf, nb) do { _Pragma("unroll")                                 \
        for (int nn = 0; nn < 2; ++nn) {                                     \
            const char* pb = ldsb + (buf) * 32768 + bBase + ((nb) + nn) * 2048; \
            bfr[(nb) + nn][0] = *(const bf16x8*)(pb + sb0);                  \
            bfr[(nb) + nn][1] = *(const bf16x8*)(pb + sb1);                  \
        } } while (0)

#define QUAD(mb, nb) do { _Pragma("unroll")                                  \
        for (int mm = 0; mm < 4; ++mm) { _Pragma("unroll")                   \
        for (int nn = 0; nn < 2; ++nn) { _Pragma("unroll")                   \
        for (int ks = 0; ks < 2; ++ks)                                       \
            acc[(mb) + mm][(nb) + nn] = __builtin_amdgcn_mfma_f32_16x16x32_bf16( \
                afr[mm][ks], bfr[(nb) + nn][ks], acc[(mb) + mm][(nb) + nn], 0, 0, 0); \
        } } } while (0)

    float4 vA0[2][2], vA1[2][2];
    int4   vB0[2][2], vB1[2][2];
    float  sB0v[2], sB1v[2];

    // Prologue: buf0 complete (issue+commit), buf1.B issued (commit at
    // loop P0/P1) -- reproduces the steady-state precondition.
    ISSUE_A(vA0, 0, 0);        ISSUE_A(vA1, 1, 0);
    ISSUE_B(vB0, sB0v, 0, 0);  ISSUE_B(vB1, sB1v, 1, 0);
    COMMIT_A(vA0, 0, 0);       COMMIT_A(vA1, 0, 1);
    COMMIT_B(vB0, sB0v, 0, 0); COMMIT_B(vB1, sB1v, 0, 1);
    ISSUE_B(vB0, sB0v, 0, 64); ISSUE_B(vB1, sB1v, 1, 64);
    LGKM0();
    BARRIER();

    const int nIter = K >> 7;   // 2 K-tiles per iteration
    for (int i = 0; i < nIter; ++i) {
        const int ke0 = i << 7;
        const int ke1 = ke0 + 64;
        int ke2 = ke0 + 128; if (ke2 >= K) ke2 -= K;
        int ke3 = ke0 + 192; if (ke3 >= K) ke3 -= K;

        // ---- P0
        ISSUE_A(vA0, 0, ke1);
        LDA4(0, 0); LDB2(0, 0);
        COMMIT_B(vB0, sB0v, 1, 0);
        BARRIER(); LGKM0();
        PRIO1(); QUAD(0, 0); PRIO0();
        BARRIER();
        // ---- P1
        ISSUE_A(vA1, 1, ke1);
        LDB2(0, 2);
        COMMIT_B(vB1, sB1v, 1, 1);
        BARRIER(); LGKM0();
        PRIO1(); QUAD(0, 2); PRIO0();
        BARRIER();
        // ---- P2
        ISSUE_B(vB0, sB0v, 0, ke2);
        LDA4(0, 4);
        COMMIT_A(vA0, 1, 0);
        BARRIER(); LGKM0();
        PRIO1(); QUAD(4, 2); PRIO0();
        BARRIER();
        // ---- P3
        ISSUE_B(vB1, sB1v, 1, ke2);
        COMMIT_A(vA1, 1, 1);
        BARRIER(); LGKM0();
        PRIO1(); QUAD(4, 0); PRIO0();
        BARRIER();
        // ---- P4
        ISSUE_A(vA0, 0, ke2);
        LDA4(1, 0); LDB2(1, 0);
        COMMIT_B(vB0, sB0v, 0, 0);
        BARRIER(); LGKM0();
        PRIO1(); QUAD(0, 0); PRIO0();
        BARRIER();
        // ---- P5
        ISSUE_A(vA1, 1, ke2);
        LDB2(1, 2);
        COMMIT_B(vB1, sB1v, 0, 1);
        BARRIER(); LGKM0();
        PRIO1(); QUAD(0, 2); PRIO0();
        BARRIER();
        // ---- P6
        ISSUE_B(vB0, sB0v, 0, ke3);
        LDA4(1, 4);
        COMMIT_A(vA0, 0, 0);
        BARRIER(); LGKM0();
        PRIO1(); QUAD(4, 2); PRIO0();
        BARRIER();
        // ---- P7
        ISSUE_B(vB1, sB1v, 1, ke3);
        COMMIT_A(vA1, 0, 1);
        BARRIER(); LGKM0();
        PRIO1(); QUAD(4, 0); PRIO0();
        BARRIER();
    }

    // Epilogue: C/D layout col=lane&15, row=(lane>>4)*4+reg (m89/m91).
#pragma unroll
    for (int n = 0; n < 4; ++n) {
        const int col = col0 + wn + n * 16 + r;
        const float bv = bias[col];
#pragma unroll
        for (int m = 0; m < 8; ++m) {
            const int row = row0 + wm + m * 16 + q * 4;
#pragma unroll
            for (int e = 0; e < 4; ++e)
                C[(size_t)(row + e) * N + col] = acc[m][n][e] + bv;
        }
    }
}

// ------------------------------------------------------- fallback (safety net)
__global__ void fallback_kernel(
    const float* __restrict__ x, const int* __restrict__ wq,
    const float* __restrict__ sc, const float* __restrict__ bias,
    float* __restrict__ out, int T, int O, int I) {
    int o = blockIdx.x * 16 + threadIdx.x;
    int t = blockIdx.y * 16 + threadIdx.y;
    if (o >= O || t >= T) return;
    const int nb = I >> 5;
    float s = 0.f;
    for (int b = 0; b < nb; ++b) {
        const float scv = sc[o * nb + b];
        float p = 0.f;
        for (int k = 0; k < 32; ++k)
            p += x[(size_t)t * I + b * 32 + k] *
                 (float)(wq[(size_t)o * I + b * 32 + k] - 128);
        s += scv * p;
    }
    out[(size_t)t * O + o] = s + bias[o];
}

// ---------------------------------------------------------------------- launch
extern "C" void kernel_launch(void* const* d_in, const int* in_sizes, int n_in,
                              void* d_out, int out_size, void* d_ws, size_t ws_size,
                              hipStream_t stream) {
    const float* x    = (const float*)d_in[0];
    const int*   wq   = (const int*)d_in[1];
    const float* sc   = (const float*)d_in[2];
    const float* bias = (const float*)d_in[3];
    float* out = (float*)d_out;

    const long long xn = in_sizes[0];
    const long long wn = in_sizes[1];
    const int O = in_sizes[3];
    const int I = (int)(wn / O);
    const int T = (int)(xn / I);

    const bool fast = (T % BM == 0) && (O % BN == 0) && (I % 128 == 0);

    if (!fast) {
        dim3 blk(16, 16);
        dim3 grd((O + 15) / 16, (T + 15) / 16);
        hipLaunchKernelGGL(fallback_kernel, grd, blk, 0, stream,
                           x, wq, sc, bias, out, T, O, I);
        return;
    }

    const int nwg = (T / BM) * (O / BN);
    hipLaunchKernelGGL(gemm_fused, dim3(nwg), dim3(512), 0, stream,
                       x, wq, sc, bias, out, T, O, I);
}